// Round 1
// baseline (359.677 us; speedup 1.0000x reference)
//
#include <hip/hip_runtime.h>
#include <stdint.h>

#define T_DIM 2048
#define V_DIM 1024
#define B_DIM 8

typedef unsigned int u32;
typedef unsigned short u16;
typedef __attribute__((ext_vector_type(8))) short s16x8;
typedef __attribute__((ext_vector_type(4))) float f32x4;

__device__ __forceinline__ u16 f2bf(float x) {
  u32 u = __builtin_bit_cast(u32, x);
  u = u + 0x7FFFu + ((u >> 16) & 1u);   // round-to-nearest-even
  return (u16)(u >> 16);
}
__device__ __forceinline__ float bf2f(u16 h) {
  u32 u = ((u32)h) << 16;
  return __builtin_bit_cast(float, u);
}

// async global->LDS, 16B per lane (m97 pattern)
#define GLD16(gp, lp) __builtin_amdgcn_global_load_lds( \
    (const __attribute__((address_space(1))) u32*)(gp), \
    (__attribute__((address_space(3))) u32*)(lp), 16, 0, 0)

// ---------------------------------------------------------------------------
// C[m,n] = sum_k A[m,k] * Bt[n,k]   (both bf16 row-major, fp32 accum)
// 128x128 tile, BK=32, 256 threads = 4 waves of 64, each wave 64x64.
// TRIL: block grid interpreted as (bn<=bm) lower-triangle of a square
//       T_DIM x T_DIM output; K limited to (bn+1)*128 (B rows are zero above
//       the diagonal anyway).
// F32OUT: write float + bias, else write bf16.
// ---------------------------------------------------------------------------
template<bool TRIL, bool F32OUT>
__global__ void __launch_bounds__(256)
gemm_bt(const u16* __restrict__ A, int lda, long long batchA,
        const u16* __restrict__ Bt, int ldb,
        void* __restrict__ Cv, int ldc, long long batchC,
        int K, float bias)
{
  int bn = blockIdx.x, bm = blockIdx.y, bz = blockIdx.z;
  if (TRIL && bn > bm) return;
  const u16* Ab = A + (long long)bz * batchA;
  int m0 = bm * 128, n0 = bn * 128;
  int kmax = K;
  if (TRIL) { int kl = (bn + 1) * 128; kmax = kl < K ? kl : K; }

  __shared__ u16 As[128 * 32];
  __shared__ u16 Bs[128 * 32];

  int tid = threadIdx.x;
  int lane = tid & 63;
  int wid = tid >> 6;
  int wm = wid >> 1, wn = wid & 1;

  f32x4 acc[4][4] = {};

  // staging map: thread t -> row r = t>>2 (+64 for pass 1), 8-elt chunk c = t&3
  int r = tid >> 2;
  int c8 = (tid & 3) * 8;
  const u16* ga0 = Ab + (long long)(m0 + r) * lda + c8;
  const u16* ga1 = ga0 + (long long)64 * lda;
  const u16* gb0 = Bt + (long long)(n0 + r) * ldb + c8;
  const u16* gb1 = gb0 + (long long)64 * ldb;
  u16* la0 = As + r * 32 + c8;       // byte offset = tid*16 (wave-contiguous)
  u16* la1 = la0 + 64 * 32;
  u16* lb0 = Bs + r * 32 + c8;
  u16* lb1 = lb0 + 64 * 32;

  int rm = lane & 15;
  int q8 = (lane >> 4) * 8;

  for (int k0 = 0; k0 < kmax; k0 += 32) {
    GLD16(ga0 + k0, la0);
    GLD16(ga1 + k0, la1);
    GLD16(gb0 + k0, lb0);
    GLD16(gb1 + k0, lb1);
    __syncthreads();
    s16x8 af[4], bfv[4];
#pragma unroll
    for (int mi = 0; mi < 4; mi++)
      af[mi] = *(const s16x8*)&As[(wm * 64 + mi * 16 + rm) * 32 + q8];
#pragma unroll
    for (int ni = 0; ni < 4; ni++)
      bfv[ni] = *(const s16x8*)&Bs[(wn * 64 + ni * 16 + rm) * 32 + q8];
#pragma unroll
    for (int mi = 0; mi < 4; mi++)
#pragma unroll
      for (int ni = 0; ni < 4; ni++)
        acc[mi][ni] = __builtin_amdgcn_mfma_f32_16x16x32_bf16(
            af[mi], bfv[ni], acc[mi][ni], 0, 0, 0);
    __syncthreads();
  }

  // C/D layout (m89-verified): col = lane&15, row = (lane>>4)*4 + reg
  int col = lane & 15;
  int rq = (lane >> 4) * 4;
#pragma unroll
  for (int mi = 0; mi < 4; mi++) {
#pragma unroll
    for (int ni = 0; ni < 4; ni++) {
      int gr = m0 + wm * 64 + mi * 16 + rq;
      int gc = n0 + wn * 64 + ni * 16 + col;
#pragma unroll
      for (int rr = 0; rr < 4; rr++) {
        if (F32OUT) {
          float* C = (float*)Cv + (long long)bz * batchC;
          C[(long long)(gr + rr) * ldc + gc] = acc[mi][ni][rr] + bias;
        } else {
          u16* C = (u16*)Cv + (long long)bz * batchC;
          C[(long long)(gr + rr) * ldc + gc] = f2bf(acc[mi][ni][rr]);
        }
      }
    }
  }
}

// ---------------------------------------------------------------------------
// transpose + cast two VxV fp32 matrices -> bf16 (dst[i][o] = src[o][i])
// ---------------------------------------------------------------------------
__global__ void transpose_cast2(const float* __restrict__ s0, u16* __restrict__ d0,
                                const float* __restrict__ s1, u16* __restrict__ d1)
{
  const float* src = blockIdx.z ? s1 : s0;
  u16* dst = blockIdx.z ? d1 : d0;
  __shared__ float tile[32][33];
  int x0 = blockIdx.x * 32, y0 = blockIdx.y * 32;
  int tx = threadIdx.x, ty = threadIdx.y;
#pragma unroll
  for (int k = 0; k < 4; k++)
    tile[ty + k * 8][tx] = src[(long long)(y0 + ty + k * 8) * V_DIM + x0 + tx];
  __syncthreads();
#pragma unroll
  for (int k = 0; k < 4; k++)
    dst[(long long)(x0 + ty + k * 8) * V_DIM + y0 + tx] = f2bf(tile[tx][ty + k * 8]);
}

__global__ void cast_bf16(const float* __restrict__ src, u16* __restrict__ dst)
{
  int i = blockIdx.x * 1024 + threadIdx.x;
#pragma unroll
  for (int k = 0; k < 4; k++) dst[i + k * 256] = f2bf(src[i + k * 256]);
}

// P[s][u] = v[s-u] for u<=s else 0  (T x T bf16)
__global__ void build_p(const float* __restrict__ v, u16* __restrict__ P)
{
  int base = blockIdx.x * 2048 + threadIdx.x;
#pragma unroll
  for (int k = 0; k < 8; k++) {
    int e = base + k * 256;
    int s = e >> 11, u = e & 2047;
    P[e] = (u <= s) ? f2bf(v[s - u]) : (u16)0;
  }
}

// G[z][t][u] = M[idx[b,t]][idx[b,u]]  — one block per (t, z)
__global__ void gather_g(const int* __restrict__ idx, const u16* __restrict__ Mb,
                         u16* __restrict__ G, int b0)
{
  int t = blockIdx.x, z = blockIdx.y;
  const int* idxrow = idx + (long long)(b0 + z) * T_DIM;
  __shared__ u16 Mrow[V_DIM];
  int tid = threadIdx.x;
  int rowid = idxrow[t];
  const u32* src = (const u32*)(Mb + (long long)rowid * V_DIM);
  u32* dstl = (u32*)Mrow;
#pragma unroll
  for (int i = tid; i < V_DIM / 2; i += 256) dstl[i] = src[i];
  __syncthreads();
  u16* Grow = G + ((long long)z * T_DIM + t) * T_DIM;
  for (int u = tid; u < T_DIM; u += 256)
    Grow[u] = Mrow[idxrow[u]];
}

// C[z][t][j] = sum_{s<=t, idx[b,s]==j} A[z][t][s]   (bf16 out, fp32 LDS accum)
__global__ void scatter_c(const int* __restrict__ idx, const u16* __restrict__ Abuf,
                          u16* __restrict__ Cb, int b0)
{
  int t = blockIdx.x, z = blockIdx.y;
  __shared__ float crow[V_DIM];
  int tid = threadIdx.x;
  for (int i = tid; i < V_DIM; i += 256) crow[i] = 0.f;
  __syncthreads();
  const int* idxrow = idx + (long long)(b0 + z) * T_DIM;
  const u16* Arow = Abuf + ((long long)z * T_DIM + t) * T_DIM;
  for (int s = tid; s <= t; s += 256) {
    float a = bf2f(Arow[s]);
    atomicAdd(&crow[idxrow[s]], a);
  }
  __syncthreads();
  u16* Crow = Cb + ((long long)z * T_DIM + t) * V_DIM;
  for (int i = tid; i < V_DIM; i += 256) Crow[i] = f2bf(crow[i]);
}

// ---------------------------------------------------------------------------
extern "C" void kernel_launch(void* const* d_in, const int* in_sizes, int n_in,
                              void* d_out, int out_size, void* d_ws, size_t ws_size,
                              hipStream_t stream)
{
  const int*   idx = (const int*)d_in[0];
  const float* v   = (const float*)d_in[1];
  const float* Wk  = (const float*)d_in[2];
  const float* Wq  = (const float*)d_in[3];
  const float* Wv  = (const float*)d_in[4];
  float* out = (float*)d_out;

  char* p = (char*)d_ws;
  const size_t SZ_VV = (size_t)V_DIM * V_DIM * 2;   // 2 MB bf16
  const size_t SZ_TT = (size_t)T_DIM * T_DIM * 2;   // 8 MB bf16
  const size_t SZ_TV = (size_t)T_DIM * V_DIM * 2;   // 4 MB bf16
  u16* WqT = (u16*)p; p += SZ_VV;
  u16* WkT = (u16*)p; p += SZ_VV;
  u16* Wvb = (u16*)p; p += SZ_VV;
  u16* Mb  = (u16*)p; p += SZ_VV;
  u16* P   = (u16*)p; p += SZ_TT;
  size_t used = (size_t)(p - (char*)d_ws);
  size_t per = 2 * SZ_TT + SZ_TV;                    // G + A + C per batch
  int nb = 8;
  while (nb > 1 && used + (size_t)nb * per > ws_size) nb >>= 1;
  u16* G    = (u16*)p; p += (size_t)nb * SZ_TT;
  u16* Abuf = (u16*)p; p += (size_t)nb * SZ_TT;
  u16* Cb   = (u16*)p;

  // one-time prep (cheap, repeated every call for graph-capture safety)
  transpose_cast2<<<dim3(32, 32, 2), dim3(32, 8), 0, stream>>>(Wq, WqT, Wk, WkT);
  cast_bf16<<<1024, 256, 0, stream>>>(Wv, Wvb);
  build_p<<<2048, 256, 0, stream>>>(v, P);
  // M = Wq^T * Wk  [V,V]
  gemm_bt<false, false><<<dim3(V_DIM / 128, V_DIM / 128, 1), 256, 0, stream>>>(
      WqT, V_DIM, 0, WkT, V_DIM, Mb, V_DIM, 0, V_DIM, 0.f);

  for (int b0 = 0; b0 < B_DIM; b0 += nb) {
    gather_g<<<dim3(T_DIM, nb), 256, 0, stream>>>(idx, Mb, G, b0);
    // A = G * P^T, lower-triangle tiles only
    gemm_bt<true, false><<<dim3(T_DIM / 128, T_DIM / 128, nb), 256, 0, stream>>>(
        G, T_DIM, (long long)T_DIM * T_DIM, P, T_DIM,
        Abuf, T_DIM, (long long)T_DIM * T_DIM, T_DIM, 0.f);
    scatter_c<<<dim3(T_DIM, nb), 256, 0, stream>>>(idx, Abuf, Cb, b0);
    // out = C * Wv^T + 0.001  (batches flattened into M)
    gemm_bt<false, true><<<dim3(V_DIM / 128, nb * T_DIM / 128, 1), 256, 0, stream>>>(
        Cb, V_DIM, 0, Wvb, V_DIM,
        out + (long long)b0 * T_DIM * V_DIM, V_DIM, 0, V_DIM, 0.001f);
  }
}

// Round 2
// 296.945 us; speedup vs baseline: 1.2113x; 1.2113x over previous
//
#include <hip/hip_runtime.h>
#include <stdint.h>

#define T_DIM 2048
#define V_DIM 1024
#define B_DIM 8

typedef unsigned int u32;
typedef unsigned short u16;
typedef __attribute__((ext_vector_type(8))) short s16x8;
typedef __attribute__((ext_vector_type(4))) float f32x4;

__device__ __forceinline__ u16 f2bf(float x) {
  u32 u = __builtin_bit_cast(u32, x);
  u = u + 0x7FFFu + ((u >> 16) & 1u);   // round-to-nearest-even
  return (u16)(u >> 16);
}

// async global->LDS, 16B per lane (m97 pattern)
#define GLD16(gp, lp) __builtin_amdgcn_global_load_lds( \
    (const __attribute__((address_space(1))) u32*)(gp), \
    (__attribute__((address_space(3))) u32*)(lp), 16, 0, 0)

// ---------------------------------------------------------------------------
// C[m,n] = sum_k A[m,k] * Bt[n,k]   (bf16 row-major, fp32 accum)
// 128x128 tile, BK=32, 256 threads = 4 waves, each wave 64x64.
// MODE 0: plain.
// MODE 1: tril output — skip bn>bm tiles, kmax=(bn+1)*128 (B rows zero above
//         diag), and zero col>row inside diagonal tiles (causal mask).
// MODE 2: causal-K — kmax=(bm+1)*128 (left operand is tril).
// F32OUT: write float + bias, else bf16.
// ---------------------------------------------------------------------------
template<int MODE, bool F32OUT>
__global__ void __launch_bounds__(256)
gemm_bt(const u16* __restrict__ A, int lda, long long batchA,
        const u16* __restrict__ Bt, int ldb, long long batchB,
        void* __restrict__ Cv, int ldc, long long batchC,
        int K, float bias)
{
  int bn = blockIdx.x, bm = blockIdx.y, bz = blockIdx.z;
  if (MODE == 1 && bn > bm) return;
  const u16* Ab = A + (long long)bz * batchA;
  const u16* Bb = Bt + (long long)bz * batchB;
  int m0 = bm * 128, n0 = bn * 128;
  int kmax = K;
  if (MODE == 1) { int kl = (bn + 1) * 128; kmax = kl < K ? kl : K; }
  if (MODE == 2) { int kl = (bm + 1) * 128; kmax = kl < K ? kl : K; }

  __shared__ u16 As[128 * 32];
  __shared__ u16 Bs[128 * 32];

  int tid = threadIdx.x;
  int lane = tid & 63;
  int wid = tid >> 6;
  int wm = wid >> 1, wn = wid & 1;

  f32x4 acc[4][4] = {};

  int r = tid >> 2;
  int c8 = (tid & 3) * 8;
  const u16* ga0 = Ab + (long long)(m0 + r) * lda + c8;
  const u16* ga1 = ga0 + (long long)64 * lda;
  const u16* gb0 = Bb + (long long)(n0 + r) * ldb + c8;
  const u16* gb1 = gb0 + (long long)64 * ldb;
  u16* la0 = As + r * 32 + c8;       // byte offset = tid*16 (wave-contiguous)
  u16* la1 = la0 + 64 * 32;
  u16* lb0 = Bs + r * 32 + c8;
  u16* lb1 = lb0 + 64 * 32;

  int rm = lane & 15;
  int q8 = (lane >> 4) * 8;

  for (int k0 = 0; k0 < kmax; k0 += 32) {
    GLD16(ga0 + k0, la0);
    GLD16(ga1 + k0, la1);
    GLD16(gb0 + k0, lb0);
    GLD16(gb1 + k0, lb1);
    __syncthreads();
    s16x8 af[4], bfv[4];
#pragma unroll
    for (int mi = 0; mi < 4; mi++)
      af[mi] = *(const s16x8*)&As[(wm * 64 + mi * 16 + rm) * 32 + q8];
#pragma unroll
    for (int ni = 0; ni < 4; ni++)
      bfv[ni] = *(const s16x8*)&Bs[(wn * 64 + ni * 16 + rm) * 32 + q8];
#pragma unroll
    for (int mi = 0; mi < 4; mi++)
#pragma unroll
      for (int ni = 0; ni < 4; ni++)
        acc[mi][ni] = __builtin_amdgcn_mfma_f32_16x16x32_bf16(
            af[mi], bfv[ni], acc[mi][ni], 0, 0, 0);
    __syncthreads();
  }

  // C/D layout (m89-verified): col = lane&15, row = (lane>>4)*4 + reg
  int col = lane & 15;
  int rq = (lane >> 4) * 4;
#pragma unroll
  for (int mi = 0; mi < 4; mi++) {
#pragma unroll
    for (int ni = 0; ni < 4; ni++) {
      int lr = wm * 64 + mi * 16 + rq;          // local row (base of 4)
      int lc = wn * 64 + ni * 16 + col;         // local col
#pragma unroll
      for (int rr = 0; rr < 4; rr++) {
        float val = acc[mi][ni][rr];
        if (MODE == 1 && bm == bn && lc > lr + rr) val = 0.f;  // causal mask
        long long off = (long long)(m0 + lr + rr) * ldc + (n0 + lc);
        if (F32OUT) {
          float* C = (float*)Cv + (long long)bz * batchC;
          C[off] = val + bias;
        } else {
          u16* C = (u16*)Cv + (long long)bz * batchC;
          C[off] = f2bf(val);
        }
      }
    }
  }
}

// ---------------------------------------------------------------------------
// transpose + cast two VxV fp32 matrices -> bf16 (dst[i][o] = src[o][i])
// ---------------------------------------------------------------------------
__global__ void transpose_cast2(const float* __restrict__ s0, u16* __restrict__ d0,
                                const float* __restrict__ s1, u16* __restrict__ d1)
{
  const float* src = blockIdx.z ? s1 : s0;
  u16* dst = blockIdx.z ? d1 : d0;
  __shared__ float tile[32][33];
  int x0 = blockIdx.x * 32, y0 = blockIdx.y * 32;
  int tx = threadIdx.x, ty = threadIdx.y;
#pragma unroll
  for (int k = 0; k < 4; k++)
    tile[ty + k * 8][tx] = src[(long long)(y0 + ty + k * 8) * V_DIM + x0 + tx];
  __syncthreads();
#pragma unroll
  for (int k = 0; k < 4; k++)
    dst[(long long)(x0 + ty + k * 8) * V_DIM + y0 + tx] = f2bf(tile[tx][ty + k * 8]);
}

__global__ void cast_bf16(const float* __restrict__ src, u16* __restrict__ dst)
{
  int i = blockIdx.x * 1024 + threadIdx.x;
#pragma unroll
  for (int k = 0; k < 4; k++) dst[i + k * 256] = f2bf(src[i + k * 256]);
}

// P[s][u] = v[s-u] for u<=s else 0  (T x T bf16), 16B stores
__global__ void build_p(const float* __restrict__ v, u16* __restrict__ P)
{
  int gid = blockIdx.x * 256 + threadIdx.x;
  int e0 = gid * 8;
  int s = e0 >> 11, u0 = e0 & 2047;
  s16x8 o;
#pragma unroll
  for (int k = 0; k < 8; k++) {
    int u = u0 + k;
    o[k] = (short)((u <= s) ? f2bf(v[s - u]) : (u16)0);
  }
  *(s16x8*)&P[e0] = o;
}

// G[z][t][u] = M[idx[b,t]][idx[b,u]] — one block per (t,z), 16B stores
__global__ void __launch_bounds__(256)
gather_g(const int* __restrict__ idx, const u16* __restrict__ Mb,
         u16* __restrict__ G, int b0)
{
  int t = blockIdx.x, z = blockIdx.y;
  const int* idxrow = idx + (long long)(b0 + z) * T_DIM;
  __shared__ u16 Mrow[V_DIM];
  int tid = threadIdx.x;
  int rowid = idxrow[t];
  const u32* src = (const u32*)(Mb + (long long)rowid * V_DIM);
  u32* dstl = (u32*)Mrow;
  dstl[tid] = src[tid];
  dstl[tid + 256] = src[tid + 256];
  __syncthreads();
  int u0 = tid * 8;
  int4 i0 = *(const int4*)&idxrow[u0];
  int4 i1 = *(const int4*)&idxrow[u0 + 4];
  s16x8 o;
  o[0] = (short)Mrow[i0.x]; o[1] = (short)Mrow[i0.y];
  o[2] = (short)Mrow[i0.z]; o[3] = (short)Mrow[i0.w];
  o[4] = (short)Mrow[i1.x]; o[5] = (short)Mrow[i1.y];
  o[6] = (short)Mrow[i1.z]; o[7] = (short)Mrow[i1.w];
  *(s16x8*)&G[((long long)z * T_DIM + t) * T_DIM + u0] = o;
}

// Yt[z][j][s] = Wv[j][idx[b,s]] — one block per (j,z), 16B stores
__global__ void __launch_bounds__(256)
gather_y(const int* __restrict__ idx, const u16* __restrict__ Wvb,
         u16* __restrict__ Yt, int b0)
{
  int j = blockIdx.x, z = blockIdx.y;
  const int* idxrow = idx + (long long)(b0 + z) * T_DIM;
  __shared__ u16 Wrow[V_DIM];
  int tid = threadIdx.x;
  const u32* src = (const u32*)(Wvb + (long long)j * V_DIM);
  u32* dstl = (u32*)Wrow;
  dstl[tid] = src[tid];
  dstl[tid + 256] = src[tid + 256];
  __syncthreads();
  int s0 = tid * 8;
  int4 i0 = *(const int4*)&idxrow[s0];
  int4 i1 = *(const int4*)&idxrow[s0 + 4];
  s16x8 o;
  o[0] = (short)Wrow[i0.x]; o[1] = (short)Wrow[i0.y];
  o[2] = (short)Wrow[i0.z]; o[3] = (short)Wrow[i0.w];
  o[4] = (short)Wrow[i1.x]; o[5] = (short)Wrow[i1.y];
  o[6] = (short)Wrow[i1.z]; o[7] = (short)Wrow[i1.w];
  *(s16x8*)&Yt[((long long)z * V_DIM + j) * T_DIM + s0] = o;
}

// ---------------------------------------------------------------------------
extern "C" void kernel_launch(void* const* d_in, const int* in_sizes, int n_in,
                              void* d_out, int out_size, void* d_ws, size_t ws_size,
                              hipStream_t stream)
{
  const int*   idx = (const int*)d_in[0];
  const float* v   = (const float*)d_in[1];
  const float* Wk  = (const float*)d_in[2];
  const float* Wq  = (const float*)d_in[3];
  const float* Wv  = (const float*)d_in[4];
  float* out = (float*)d_out;

  char* p = (char*)d_ws;
  const size_t SZ_VV = (size_t)V_DIM * V_DIM * 2;   // 2 MB bf16
  const size_t SZ_TT = (size_t)T_DIM * T_DIM * 2;   // 8 MB bf16
  const size_t SZ_VT = (size_t)V_DIM * T_DIM * 2;   // 4 MB bf16
  u16* WqT = (u16*)p; p += SZ_VV;
  u16* WkT = (u16*)p; p += SZ_VV;
  u16* Wvb = (u16*)p; p += SZ_VV;
  u16* Mb  = (u16*)p; p += SZ_VV;
  u16* P   = (u16*)p; p += SZ_TT;
  size_t used = (size_t)(p - (char*)d_ws);
  size_t per = 2 * SZ_TT + SZ_VT;                    // G + A + Yt per batch
  int nb = 8;
  while (nb > 1 && used + (size_t)nb * per > ws_size) nb >>= 1;
  u16* G    = (u16*)p; p += (size_t)nb * SZ_TT;
  u16* Abuf = (u16*)p; p += (size_t)nb * SZ_TT;
  u16* Yt   = (u16*)p;

  transpose_cast2<<<dim3(32, 32, 2), dim3(32, 8), 0, stream>>>(Wq, WqT, Wk, WkT);
  cast_bf16<<<1024, 256, 0, stream>>>(Wv, Wvb);
  build_p<<<2048, 256, 0, stream>>>(v, P);
  // M = Wq^T * Wk  [V,V]
  gemm_bt<0, false><<<dim3(V_DIM / 128, V_DIM / 128, 1), 256, 0, stream>>>(
      WqT, V_DIM, 0, WkT, V_DIM, 0, Mb, V_DIM, 0, V_DIM, 0.f);

  for (int b0 = 0; b0 < B_DIM; b0 += nb) {
    gather_g<<<dim3(T_DIM, nb), 256, 0, stream>>>(idx, Mb, G, b0);
    gather_y<<<dim3(V_DIM, nb), 256, 0, stream>>>(idx, Wvb, Yt, b0);
    // A = tril(G * P^T), lower-triangle tiles only, diag masked
    gemm_bt<1, false><<<dim3(T_DIM / 128, T_DIM / 128, nb), 256, 0, stream>>>(
        G, T_DIM, (long long)T_DIM * T_DIM, P, T_DIM, 0,
        Abuf, T_DIM, (long long)T_DIM * T_DIM, T_DIM, 0.f);
    // out = A * Yt^T + 0.001, K limited to (bm+1)*128 per row-block
    gemm_bt<2, true><<<dim3(V_DIM / 128, T_DIM / 128, nb), 256, 0, stream>>>(
        Abuf, T_DIM, (long long)T_DIM * T_DIM, Yt, T_DIM, (long long)V_DIM * T_DIM,
        out + (long long)b0 * T_DIM * V_DIM, V_DIM, (long long)T_DIM * V_DIM,
        T_DIM, 0.001f);
  }
}

// Round 3
// 260.068 us; speedup vs baseline: 1.3830x; 1.1418x over previous
//
#include <hip/hip_runtime.h>
#include <stdint.h>

#define T_DIM 2048
#define V_DIM 1024
#define B_DIM 8
#define NT 16            // T_DIM/128
#define NTRIL 136        // NT*(NT+1)/2

typedef unsigned int u32;
typedef unsigned short u16;
typedef __attribute__((ext_vector_type(8))) short s16x8;
typedef __attribute__((ext_vector_type(4))) float f32x4;

__device__ __forceinline__ u16 f2bf(float x) {
  u32 u = __builtin_bit_cast(u32, x);
  u = u + 0x7FFFu + ((u >> 16) & 1u);   // round-to-nearest-even
  return (u16)(u >> 16);
}

// async global->LDS, 16B per lane (m97 pattern)
#define GLD16(gp, lp) __builtin_amdgcn_global_load_lds( \
    (const __attribute__((address_space(1))) u32*)(gp), \
    (__attribute__((address_space(3))) u32*)(lp), 16, 0, 0)

// ---------------------------------------------------------------------------
// C[m,n] = sum_k A[m,k] * Bt[n,k]   (bf16 row-major, fp32 accum)
// 128x128 tile, BK=32, 256 threads = 4 waves, each wave 64x64.
// LDS layout XOR-swizzled: slot c of row r holds global chunk (c - (r>>1))&3,
// so ds_read_b128 fragment reads spread rows 0..7 over all 8 bank groups
// (2-way aliasing = free, vs 8-way = 2.94x before).
// MODE 0: plain; grid (nx, ny, nz).
// MODE 1: tril output — grid (nb, 136); tile decoded bn-DESCENDING
//         (heavy-first), kmax=(bn+1)*128, diag tiles causal-masked.
// MODE 2: causal-K — grid (8, nb, 16); bm = 15 - z (heavy-first),
//         kmax=(bm+1)*128 (left operand is tril).
// F32OUT: write float + bias, else bf16.
// ---------------------------------------------------------------------------
template<int MODE, bool F32OUT>
__global__ void __launch_bounds__(256)
gemm_bt(const u16* __restrict__ A, int lda, long long batchA,
        const u16* __restrict__ Bt, int ldb, long long batchB,
        void* __restrict__ Cv, int ldc, long long batchC,
        int K, float bias)
{
  int bn, bm, bz;
  if (MODE == 0) {
    bn = blockIdx.x; bm = blockIdx.y; bz = blockIdx.z;
  } else if (MODE == 1) {
    bz = blockIdx.x;
    int tau = blockIdx.y;          // 0..135, bn descending (heavy first)
    int b = NT - 1, off = 0;
    while (tau >= off + (NT - b)) { off += NT - b; b--; }
    bn = b; bm = b + (tau - off);
  } else {                          // MODE 2
    bn = blockIdx.x; bz = blockIdx.y; bm = (NT - 1) - blockIdx.z;
  }
  const u16* Ab = A + (long long)bz * batchA;
  const u16* Bb = Bt + (long long)bz * batchB;
  int m0 = bm * 128, n0 = bn * 128;
  int kmax = K;
  if (MODE == 1) { int kl = (bn + 1) * 128; kmax = kl < K ? kl : K; }
  if (MODE == 2) { int kl = (bm + 1) * 128; kmax = kl < K ? kl : K; }

  __shared__ u16 As[128 * 32];
  __shared__ u16 Bs[128 * 32];

  int tid = threadIdx.x;
  int lane = tid & 63;
  int wid = tid >> 6;
  int wm = wid >> 1, wn = wid & 1;

  f32x4 acc[4][4] = {};

  // staging: thread t covers row r=t>>2 (and r+64), LDS slot (t&3).
  // Global chunk loaded into slot c is (c - (r>>1))&3  (XOR-ish swizzle).
  int r = tid >> 2;
  int cslot = tid & 3;
  int cg = (((cslot - (r >> 1)) & 3)) * 8;    // element offset of global chunk
  const u16* ga0 = Ab + (long long)(m0 + r) * lda + cg;
  const u16* ga1 = ga0 + (long long)64 * lda;  // (r+64)>>1 & 3 == (r>>1)&3 (+32)
  const u16* gb0 = Bb + (long long)(n0 + r) * ldb + cg;
  const u16* gb1 = gb0 + (long long)64 * ldb;
  u16* la0 = As + r * 32 + cslot * 8;          // byte offset = tid*16
  u16* la1 = la0 + 64 * 32;
  u16* lb0 = Bs + r * 32 + cslot * 8;
  u16* lb1 = lb0 + 64 * 32;

  int rm = lane & 15;
  int q8 = ((((lane >> 4) + (rm >> 1)) & 3)) * 8;   // physical chunk to read

  for (int k0 = 0; k0 < kmax; k0 += 32) {
    GLD16(ga0 + k0, la0);
    GLD16(ga1 + k0, la1);
    GLD16(gb0 + k0, lb0);
    GLD16(gb1 + k0, lb1);
    __syncthreads();
    s16x8 af[4], bfv[4];
#pragma unroll
    for (int mi = 0; mi < 4; mi++)
      af[mi] = *(const s16x8*)&As[(wm * 64 + mi * 16 + rm) * 32 + q8];
#pragma unroll
    for (int ni = 0; ni < 4; ni++)
      bfv[ni] = *(const s16x8*)&Bs[(wn * 64 + ni * 16 + rm) * 32 + q8];
#pragma unroll
    for (int mi = 0; mi < 4; mi++)
#pragma unroll
      for (int ni = 0; ni < 4; ni++)
        acc[mi][ni] = __builtin_amdgcn_mfma_f32_16x16x32_bf16(
            af[mi], bfv[ni], acc[mi][ni], 0, 0, 0);
    __syncthreads();
  }

  // C/D layout (m89-verified): col = lane&15, row = (lane>>4)*4 + reg
  int col = lane & 15;
  int rq = (lane >> 4) * 4;
#pragma unroll
  for (int mi = 0; mi < 4; mi++) {
#pragma unroll
    for (int ni = 0; ni < 4; ni++) {
      int lr = wm * 64 + mi * 16 + rq;          // local row (base of 4)
      int lc = wn * 64 + ni * 16 + col;         // local col
#pragma unroll
      for (int rr = 0; rr < 4; rr++) {
        float val = acc[mi][ni][rr];
        if (MODE == 1 && bm == bn && lc > lr + rr) val = 0.f;  // causal mask
        long long off = (long long)(m0 + lr + rr) * ldc + (n0 + lc);
        if (F32OUT) {
          float* C = (float*)Cv + (long long)bz * batchC;
          C[off] = val + bias;
        } else {
          u16* C = (u16*)Cv + (long long)bz * batchC;
          C[off] = f2bf(val);
        }
      }
    }
  }
}

// ---------------------------------------------------------------------------
// transpose + cast two VxV fp32 matrices -> bf16 (dst[i][o] = src[o][i])
// ---------------------------------------------------------------------------
__global__ void transpose_cast2(const float* __restrict__ s0, u16* __restrict__ d0,
                                const float* __restrict__ s1, u16* __restrict__ d1)
{
  const float* src = blockIdx.z ? s1 : s0;
  u16* dst = blockIdx.z ? d1 : d0;
  __shared__ float tile[32][33];
  int x0 = blockIdx.x * 32, y0 = blockIdx.y * 32;
  int tx = threadIdx.x, ty = threadIdx.y;
#pragma unroll
  for (int k = 0; k < 4; k++)
    tile[ty + k * 8][tx] = src[(long long)(y0 + ty + k * 8) * V_DIM + x0 + tx];
  __syncthreads();
#pragma unroll
  for (int k = 0; k < 4; k++)
    dst[(long long)(x0 + ty + k * 8) * V_DIM + y0 + tx] = f2bf(tile[tx][ty + k * 8]);
}

__global__ void cast_bf16(const float* __restrict__ src, u16* __restrict__ dst)
{
  int i = blockIdx.x * 1024 + threadIdx.x;
#pragma unroll
  for (int k = 0; k < 4; k++) dst[i + k * 256] = f2bf(src[i + k * 256]);
}

// P[s][u] = v[s-u] for u<=s else 0  (T x T bf16), 16B stores
__global__ void build_p(const float* __restrict__ v, u16* __restrict__ P)
{
  int gid = blockIdx.x * 256 + threadIdx.x;
  int e0 = gid * 8;
  int s = e0 >> 11, u0 = e0 & 2047;
  s16x8 o;
#pragma unroll
  for (int k = 0; k < 8; k++) {
    int u = u0 + k;
    o[k] = (short)((u <= s) ? f2bf(v[s - u]) : (u16)0);
  }
  *(s16x8*)&P[e0] = o;
}

// G[z][t][u] = M[idx[b,t]][idx[b,u]] — one block per (t,z), 16B stores
__global__ void __launch_bounds__(256)
gather_g(const int* __restrict__ idx, const u16* __restrict__ Mb,
         u16* __restrict__ G, int b0)
{
  int t = blockIdx.x, z = blockIdx.y;
  const int* idxrow = idx + (long long)(b0 + z) * T_DIM;
  __shared__ u16 Mrow[V_DIM];
  int tid = threadIdx.x;
  int rowid = idxrow[t];
  const u32* src = (const u32*)(Mb + (long long)rowid * V_DIM);
  u32* dstl = (u32*)Mrow;
  dstl[tid] = src[tid];
  dstl[tid + 256] = src[tid + 256];
  __syncthreads();
  int u0 = tid * 8;
  int4 i0 = *(const int4*)&idxrow[u0];
  int4 i1 = *(const int4*)&idxrow[u0 + 4];
  s16x8 o;
  o[0] = (short)Mrow[i0.x]; o[1] = (short)Mrow[i0.y];
  o[2] = (short)Mrow[i0.z]; o[3] = (short)Mrow[i0.w];
  o[4] = (short)Mrow[i1.x]; o[5] = (short)Mrow[i1.y];
  o[6] = (short)Mrow[i1.z]; o[7] = (short)Mrow[i1.w];
  *(s16x8*)&G[((long long)z * T_DIM + t) * T_DIM + u0] = o;
}

// Yt[z][j][s] = Wv[j][idx[b,s]] — one block per (j,z), 16B stores
__global__ void __launch_bounds__(256)
gather_y(const int* __restrict__ idx, const u16* __restrict__ Wvb,
         u16* __restrict__ Yt, int b0)
{
  int j = blockIdx.x, z = blockIdx.y;
  const int* idxrow = idx + (long long)(b0 + z) * T_DIM;
  __shared__ u16 Wrow[V_DIM];
  int tid = threadIdx.x;
  const u32* src = (const u32*)(Wvb + (long long)j * V_DIM);
  u32* dstl = (u32*)Wrow;
  dstl[tid] = src[tid];
  dstl[tid + 256] = src[tid + 256];
  __syncthreads();
  int s0 = tid * 8;
  int4 i0 = *(const int4*)&idxrow[s0];
  int4 i1 = *(const int4*)&idxrow[s0 + 4];
  s16x8 o;
  o[0] = (short)Wrow[i0.x]; o[1] = (short)Wrow[i0.y];
  o[2] = (short)Wrow[i0.z]; o[3] = (short)Wrow[i0.w];
  o[4] = (short)Wrow[i1.x]; o[5] = (short)Wrow[i1.y];
  o[6] = (short)Wrow[i1.z]; o[7] = (short)Wrow[i1.w];
  *(s16x8*)&Yt[((long long)z * V_DIM + j) * T_DIM + s0] = o;
}

// ---------------------------------------------------------------------------
extern "C" void kernel_launch(void* const* d_in, const int* in_sizes, int n_in,
                              void* d_out, int out_size, void* d_ws, size_t ws_size,
                              hipStream_t stream)
{
  const int*   idx = (const int*)d_in[0];
  const float* v   = (const float*)d_in[1];
  const float* Wk  = (const float*)d_in[2];
  const float* Wq  = (const float*)d_in[3];
  const float* Wv  = (const float*)d_in[4];
  float* out = (float*)d_out;

  char* p = (char*)d_ws;
  const size_t SZ_VV = (size_t)V_DIM * V_DIM * 2;   // 2 MB bf16
  const size_t SZ_TT = (size_t)T_DIM * T_DIM * 2;   // 8 MB bf16
  const size_t SZ_VT = (size_t)V_DIM * T_DIM * 2;   // 4 MB bf16
  u16* WqT = (u16*)p; p += SZ_VV;
  u16* WkT = (u16*)p; p += SZ_VV;
  u16* Wvb = (u16*)p; p += SZ_VV;
  u16* Mb  = (u16*)p; p += SZ_VV;
  u16* P   = (u16*)p; p += SZ_TT;
  size_t used = (size_t)(p - (char*)d_ws);
  size_t per = 2 * SZ_TT + SZ_VT;                    // G + A + Yt per batch
  int nb = 8;
  while (nb > 1 && used + (size_t)nb * per > ws_size) nb >>= 1;
  u16* G    = (u16*)p; p += (size_t)nb * SZ_TT;
  u16* Abuf = (u16*)p; p += (size_t)nb * SZ_TT;
  u16* Yt   = (u16*)p;

  transpose_cast2<<<dim3(32, 32, 2), dim3(32, 8), 0, stream>>>(Wq, WqT, Wk, WkT);
  cast_bf16<<<1024, 256, 0, stream>>>(Wv, Wvb);
  build_p<<<2048, 256, 0, stream>>>(v, P);
  // M = Wq^T * Wk  [V,V]
  gemm_bt<0, false><<<dim3(V_DIM / 128, V_DIM / 128, 1), 256, 0, stream>>>(
      WqT, V_DIM, 0, WkT, V_DIM, 0, Mb, V_DIM, 0, V_DIM, 0.f);

  for (int b0 = 0; b0 < B_DIM; b0 += nb) {
    gather_g<<<dim3(T_DIM, nb), 256, 0, stream>>>(idx, Mb, G, b0);
    gather_y<<<dim3(V_DIM, nb), 256, 0, stream>>>(idx, Wvb, Yt, b0);
    // A = tril(G * P^T): only tril tiles, bn-descending heavy-first
    gemm_bt<1, false><<<dim3(nb, NTRIL, 1), 256, 0, stream>>>(
        G, T_DIM, (long long)T_DIM * T_DIM, P, T_DIM, 0,
        Abuf, T_DIM, (long long)T_DIM * T_DIM, T_DIM, 0.f);
    // out = A * Yt^T + 0.001, kmax=(bm+1)*128, bm descending heavy-first
    gemm_bt<2, true><<<dim3(V_DIM / 128, nb, NT), 256, 0, stream>>>(
        Abuf, T_DIM, (long long)T_DIM * T_DIM, Yt, T_DIM, (long long)V_DIM * T_DIM,
        out + (long long)b0 * T_DIM * V_DIM, V_DIM, (long long)T_DIM * V_DIM,
        T_DIM, 0.001f);
  }
}